// Round 5
// baseline (998.925 us; speedup 1.0000x reference)
//
#include <hip/hip_runtime.h>
#include <cstdint>

#define D_MODEL 1024
#define RANK 128
#define K_RANK_ 128
#define N_KNOW 32768
#define COARSE_K 64
#define FINE_K 16
#define NTOK 4096
#define MSEL 96
#define DELTA 1.6e-3f
#define SC 4096
#define OCAP 768
#define LSLOT 6

using u32 = unsigned int;
using u64 = unsigned long long;
typedef _Float16 half8 __attribute__((ext_vector_type(8)));
typedef __attribute__((ext_vector_type(4))) float f32x4;

__device__ __forceinline__ u32 ordf(float v) {
    u32 u = __float_as_uint(v);
    return (u & 0x80000000u) ? ~u : (u | 0x80000000u);
}
__device__ __forceinline__ float unordf(u32 o) {
    return (o & 0x80000000u) ? __uint_as_float(o ^ 0x80000000u)
                             : __uint_as_float(~o);
}
__device__ __forceinline__ ushort f2h(float f) {
    union { _Float16 h; ushort u; } cv; cv.h = (_Float16)f; return cv.u;
}
__device__ __forceinline__ void gload16(const void* g, void* l) {
    __builtin_amdgcn_global_load_lds(
        (const __attribute__((address_space(1))) char*)g,
        (__attribute__((address_space(3))) char*)l, 16, 0, 0);
}

// ---------------------------------------------------------------------------
__global__ __launch_bounds__(256)
void kcvt_x(const float* __restrict__ in, ushort* __restrict__ xh)
{
    int i = blockIdx.x * 256 + threadIdx.x;
    float4 v = ((const float4*)in)[i];
    ((ushort4*)xh)[i] = make_ushort4(f2h(v.x), f2h(v.y), f2h(v.z), f2h(v.w));
}

// ---------------------------------------------------------------------------
__global__ __launch_bounds__(256)
void kcvt_wt(const float* __restrict__ W, ushort* __restrict__ out, int col0)
{
    __shared__ float tile[32][33];
    const int nb = blockIdx.x * 32;
    const int kb = blockIdx.y * 32;
    const int tx = threadIdx.x & 31, ty = threadIdx.x >> 5;
#pragma unroll
    for (int q = 0; q < 4; ++q)
        tile[ty + q * 8][tx] = W[(size_t)(kb + ty + q * 8) * N_KNOW + col0 + nb + tx];
    __syncthreads();
#pragma unroll
    for (int q = 0; q < 4; ++q) {
        float v = tile[tx][ty + q * 8];
        out[(size_t)(nb + ty + q * 8) * D_MODEL + kb + tx] = f2h(v);
    }
}

// ---------------------------------------------------------------------------
// K1: fp16 MFMA GEMM per stripe. MODE 0: dense f32 logits to L (stripe 0).
// MODE 1: fused filter vs per-token running tau (=R96[95]); survivors are
// LDS-aggregated per token then appended to ovf with one reservation atomic
// per (block,token).
// ---------------------------------------------------------------------------
template <int MODE>
__global__ __launch_bounds__(256)
void k1f(const ushort* __restrict__ xh, const ushort* __restrict__ wt,
         float* __restrict__ L, u64* __restrict__ ovf, int* __restrict__ cnt,
         const u64* __restrict__ R96, int col0)
{
    __shared__ ushort lds[2][8192];
    __shared__ u64 tauk[128];
    __shared__ u64 lslots[128][LSLOT];
    __shared__ int lcnt[128];

    const int tid = threadIdx.x;
    const int nwg = gridDim.x * gridDim.y;
    int wfl = blockIdx.x * gridDim.y + blockIdx.y;
    wfl = (wfl & 7) * (nwg >> 3) + (wfl >> 3);
    const int bn = (wfl / (NTOK / 128)) * 128;
    const int bm = (wfl % (NTOK / 128)) * 128;

    const int lane = tid & 63;
    const int wv = tid >> 6;
    const int wr = wv >> 1, wc = wv & 1;
    const int lrow = lane & 15, g = lane >> 4;

    const ushort* gsrc[4];
#pragma unroll
    for (int i = 0; i < 4; ++i) {
        const int o = tid + ((i & 1) << 8);
        const int row = o >> 2;
        const int kp = (((o & 3) ^ ((o >> 3) & 3)) << 3);
        if (i < 2) gsrc[i] = xh + (size_t)(bm + row) * D_MODEL + kp;
        else       gsrc[i] = wt + (size_t)(bn + row) * D_MODEL + kp;
    }

    int aoff[4], boff[4];
#pragma unroll
    for (int m = 0; m < 4; ++m) {
        int row = wr * 64 + m * 16 + lrow;
        aoff[m] = row * 32 + ((g ^ ((row >> 1) & 3)) << 3);
    }
#pragma unroll
    for (int n = 0; n < 4; ++n) {
        int row = wc * 64 + n * 16 + lrow;
        boff[n] = row * 32 + ((g ^ ((row >> 1) & 3)) << 3);
    }

    f32x4 acc[4][4];
#pragma unroll
    for (int m = 0; m < 4; ++m)
#pragma unroll
        for (int n = 0; n < 4; ++n) acc[m][n] = (f32x4)(0.f);

#pragma unroll
    for (int i = 0; i < 4; ++i)
        gload16(gsrc[i], &lds[0][(tid + (i << 8)) * 8]);

    if (MODE == 1 && tid < 128) {
        tauk[tid] = R96[(size_t)(bm + tid) * MSEL + (MSEL - 1)];
        lcnt[tid] = 0;
    }

    const int NKB = D_MODEL / 32;
    for (int kb = 0; kb < NKB; ++kb) {
        const int cur = kb & 1;
        __syncthreads();
        if (kb + 1 < NKB) {
#pragma unroll
            for (int i = 0; i < 4; ++i)
                gload16(gsrc[i] + (kb + 1) * 32,
                        &lds[cur ^ 1][(tid + (i << 8)) * 8]);
        }
        const ushort* lb = lds[cur];
        half8 ah[4], bh[4];
#pragma unroll
        for (int m = 0; m < 4; ++m) ah[m] = *(const half8*)(const void*)(lb + aoff[m]);
#pragma unroll
        for (int n = 0; n < 4; ++n) bh[n] = *(const half8*)(const void*)(lb + 4096 + boff[n]);
#pragma unroll
        for (int m = 0; m < 4; ++m)
#pragma unroll
            for (int n = 0; n < 4; ++n)
                acc[m][n] = __builtin_amdgcn_mfma_f32_16x16x32_f16(ah[m], bh[n], acc[m][n], 0, 0, 0);
    }

    const int grow4 = wr * 64 + g * 4;

    if (MODE == 0) {
        const int crow = bm + grow4;
        const int ccol = bn + wc * 64 + lrow;
#pragma unroll
        for (int m = 0; m < 4; ++m)
#pragma unroll
            for (int n = 0; n < 4; ++n)
#pragma unroll
                for (int r = 0; r < 4; ++r)
                    L[(size_t)(crow + m * 16 + r) * SC + ccol + n * 16] = acc[m][n][r];
    } else {
        __syncthreads();   // lcnt/tauk visible; all compute done
        u64 taur[4][4];
#pragma unroll
        for (int m = 0; m < 4; ++m)
#pragma unroll
            for (int r = 0; r < 4; ++r) taur[m][r] = tauk[grow4 + m * 16 + r];

#pragma unroll
        for (int m = 0; m < 4; ++m)
#pragma unroll
            for (int n = 0; n < 4; ++n)
#pragma unroll
                for (int r = 0; r < 4; ++r) {
                    const int rl = grow4 + m * 16 + r;
                    const int gc = col0 + bn + wc * 64 + lrow + n * 16;
                    u64 key = ((u64)ordf(acc[m][n][r]) << 32) | (u32)(N_KNOW - 1 - gc);
                    if (key > taur[m][r]) {
                        int lp = atomicAdd(&lcnt[rl], 1);
                        if (lp < LSLOT) lslots[rl][lp] = key;
                        else {
                            int gp = atomicAdd(&cnt[bm + rl], 1);
                            if (gp < OCAP) ovf[(size_t)(bm + rl) * OCAP + gp] = key;
                        }
                    }
                }
        __syncthreads();
        if (tid < 128) {
            int c = lcnt[tid]; if (c > LSLOT) c = LSLOT;
            if (c > 0) {
                int base = atomicAdd(&cnt[bm + tid], c);
                for (int i = 0; i < c; ++i) {
                    int gp = base + i;
                    if (gp < OCAP) ovf[(size_t)(bm + tid) * OCAP + gp] = lslots[tid][i];
                }
            }
        }
    }
}

// ---------------------------------------------------------------------------
// K2: per-token top-96 from dense stripe 0
// ---------------------------------------------------------------------------
template <int M, int VPT>
__global__ __launch_bounds__(256)
void k2_topk(const float* __restrict__ L, u64* __restrict__ R, int col0)
{
    const int tt = blockIdx.x;
    const int tid = threadIdx.x;

    __shared__ u64 buf[4224];
    __shared__ int scnt;
    __shared__ int sred[4];

    u64 key[VPT];
    const float* row = L + (size_t)tt * SC;
#pragma unroll
    for (int j = 0; j < VPT; ++j) {
        int c = (j << 8) + tid;
        key[j] = ((u64)ordf(row[c]) << 32) | (u32)(N_KNOW - 1 - (col0 + c));
    }

    u32 lo = 0, hi = 0xFFFFFFFFu;
    for (int it = 0; it < 28; ++it) {
        if (hi - lo <= 1) break;
        u32 mid = lo + ((hi - lo) >> 1);
        int c = 0;
#pragma unroll
        for (int j = 0; j < VPT; ++j) c += ((u32)(key[j] >> 32) > mid) ? 1 : 0;
#pragma unroll
        for (int o = 32; o; o >>= 1) c += __shfl_xor(c, o);
        if ((tid & 63) == 0) sred[tid >> 6] = c;
        __syncthreads();
        c = sred[0] + sred[1] + sred[2] + sred[3];
        __syncthreads();
        if (c >= M) { lo = mid; if (c <= 768) break; }
        else hi = mid;
    }
    u64 tkey = ((u64)lo << 32) | 0xFFFFFFFFull;
    if (tid == 0) scnt = 0;
    __syncthreads();

#pragma unroll
    for (int j = 0; j < VPT; ++j)
        if (key[j] > tkey) {
            int p = atomicAdd(&scnt, 1);
            if (p < 4224) buf[p] = key[j];
        }
    __syncthreads();

    const int n = min(scnt, 4224);
    for (int i = tid; i < n; i += 256) {
        u64 ki = buf[i];
        int r = 0;
        for (int j = 0; j < n; ++j) r += (buf[j] > ki) ? 1 : 0;
        if (r < M) R[(size_t)tt * M + r] = ki;
    }
}

// ---------------------------------------------------------------------------
// K2m: merge R96 with per-token overflow list -> new sorted top-96; reset cnt
// ---------------------------------------------------------------------------
__global__ __launch_bounds__(256)
void k2m(u64* __restrict__ R96, const u64* __restrict__ ovf, int* __restrict__ cnt)
{
    const int tt = blockIdx.x;
    const int tid = threadIdx.x;

    __shared__ u64 cand[MSEL + OCAP];
    __shared__ u64 comp[MSEL + OCAP];
    __shared__ int scnt;
    __shared__ int sred[4];

    const int mo = min(cnt[tt], OCAP);
    const int m = MSEL + mo;
    for (int i = tid; i < MSEL; i += 256) cand[i] = R96[(size_t)tt * MSEL + i];
    for (int i = tid; i < mo; i += 256) cand[MSEL + i] = ovf[(size_t)tt * OCAP + i];
    __syncthreads();

    u32 lo = 0, hi = 0xFFFFFFFFu;
    for (int it = 0; it < 30; ++it) {
        if (hi - lo <= 1) break;
        u32 mid = lo + ((hi - lo) >> 1);
        int c = 0;
        for (int i = tid; i < m; i += 256) c += ((u32)(cand[i] >> 32) > mid) ? 1 : 0;
#pragma unroll
        for (int o = 32; o; o >>= 1) c += __shfl_xor(c, o);
        if ((tid & 63) == 0) sred[tid >> 6] = c;
        __syncthreads();
        c = sred[0] + sred[1] + sred[2] + sred[3];
        __syncthreads();
        if (c >= MSEL) { lo = mid; if (c <= 512) break; }
        else hi = mid;
    }
    if (tid == 0) scnt = 0;
    __syncthreads();
    for (int i = tid; i < m; i += 256)
        if ((u32)(cand[i] >> 32) > lo) {
            int p = atomicAdd(&scnt, 1);
            if (p < MSEL + OCAP) comp[p] = cand[i];
        }
    __syncthreads();
    const int n = min(scnt, MSEL + OCAP);
    for (int i = tid; i < n; i += 256) {
        u64 ki = comp[i];
        int r = 0;
        for (int j = 0; j < n; ++j) r += (comp[j] > ki) ? 1 : 0;
        if (r < MSEL) R96[(size_t)tt * MSEL + r] = ki;
    }
    if (tid == 0) cnt[tt] = 0;
}

// ---------------------------------------------------------------------------
// K2b pipeline: band -> exec (parallel exact f32 re-score) -> final
// ---------------------------------------------------------------------------
__global__ __launch_bounds__(256)
void k2b_band(const u64* __restrict__ R96, u32* __restrict__ jobs,
              int* __restrict__ jobCount, u32* __restrict__ band)
{
    __shared__ float sv[4][MSEL];
    const int tid = threadIdx.x;
    const int w = tid >> 6, lane = tid & 63;
    const int tt = blockIdx.x * 4 + w;

    sv[w][lane] = unordf((u32)(R96[(size_t)tt * MSEL + lane] >> 32));
    if (lane < MSEL - 64)
        sv[w][lane + 64] = unordf((u32)(R96[(size_t)tt * MSEL + lane + 64] >> 32));
    __syncthreads();

    const float t = sv[w][COARSE_K - 1];
    int cg = 0, cl = 0;
    for (int j = lane; j < MSEL; j += 64) {
        cg += (sv[w][j] > t + DELTA) ? 1 : 0;
        cl += (sv[w][j] < t - DELTA) ? 1 : 0;
    }
#pragma unroll
    for (int o = 32; o; o >>= 1) { cg += __shfl_xor(cg, o); cl += __shfl_xor(cl, o); }

    int lo = cg, hi = MSEL - 1 - cl;
    if (lo > COARSE_K - 1) lo = COARSE_K - 1;
    if (hi < COARSE_K - 1) hi = COARSE_K - 1;

    u32 b;
    if (lo == COARSE_K - 1 && hi == COARSE_K - 1) {
        b = 0x80000000u | 63u | (63u << 8);
    } else {
        int nj = hi - lo + 1;
        int base = 0;
        if (lane == 0) base = atomicAdd(jobCount, nj);
        base = __shfl(base, 0);
        for (int k = lane; k < nj; k += 64)
            jobs[base + k] = ((u32)tt << 8) | (u32)(lo + k);
        b = (u32)lo | ((u32)hi << 8);
    }
    if (lane == 0) band[tt] = b;
}

__global__ __launch_bounds__(256)
void k2b_exec(const u32* __restrict__ jobs, const int* __restrict__ jobCount,
              const u64* __restrict__ R96, const float* __restrict__ x,
              const float* __restrict__ W, u64* __restrict__ nk)
{
    __shared__ float red[4];
    const int tid = threadIdx.x;
    const int n = *jobCount;
    for (int j = blockIdx.x; j < n; j += gridDim.x) {
        u32 jd = jobs[j];
        int tt = jd >> 8, idx = jd & 255;
        u64 key = R96[(size_t)tt * MSEL + idx];
        int col = (N_KNOW - 1) - (int)(u32)(key & 0xFFFFFFFFu);
        float p = 0.f;
#pragma unroll
        for (int q = 0; q < 4; ++q) {
            int k = tid + q * 256;
            p = fmaf(x[(size_t)tt * D_MODEL + k], W[(size_t)k * N_KNOW + col], p);
        }
#pragma unroll
        for (int o = 32; o; o >>= 1) p += __shfl_xor(p, o);
        if ((tid & 63) == 0) red[tid >> 6] = p;
        __syncthreads();
        if (tid == 0) {
            float e = red[0] + red[1] + red[2] + red[3];
            nk[(size_t)tt * MSEL + idx] = ((u64)ordf(e) << 32) | (key & 0xFFFFFFFFu);
        }
        __syncthreads();
    }
}

__global__ __launch_bounds__(128)
void k2b_final(const u64* __restrict__ R96, const u64* __restrict__ nk,
               const u32* __restrict__ band, u64* __restrict__ R64)
{
    const int tt = blockIdx.x;
    const int tid = threadIdx.x;
    __shared__ u64 keys[MSEL];
    __shared__ u64 nkk[MSEL];

    const u32 b = band[tt];
    if (tid < MSEL) keys[tid] = R96[(size_t)tt * MSEL + tid];
    const int lo = b & 0xFF, hi = (b >> 8) & 0xFF;
    const bool trivial = (b & 0x80000000u) != 0;
    if (!trivial && tid >= lo && tid <= hi && tid < MSEL)
        nkk[tid] = nk[(size_t)tt * MSEL + tid];
    __syncthreads();

    if (trivial) {
        if (tid < COARSE_K) R64[(size_t)tt * COARSE_K + tid] = keys[tid];
        return;
    }
    if (tid < lo) R64[(size_t)tt * COARSE_K + tid] = keys[tid];
    const int mwin = COARSE_K - lo;
    if (tid >= lo && tid <= hi) {
        u64 me = nkk[tid];
        int r = 0;
        for (int j = lo; j <= hi; ++j) r += (nkk[j] > me) ? 1 : 0;
        if (r < mwin) R64[(size_t)tt * COARSE_K + lo + r] = keys[tid];
    }
}

// ---------------------------------------------------------------------------
// K3a: fine scores + top-16 + softmax weights
// ---------------------------------------------------------------------------
__global__ __launch_bounds__(256)
void k3a(const float* __restrict__ h, const float* __restrict__ Wq,
         const float* __restrict__ Kall, const u64* __restrict__ R,
         int* __restrict__ fidx, float* __restrict__ fw)
{
    const int tt = blockIdx.x;
    const int tid = threadIdx.x;

    __shared__ float hrow[RANK];
    __shared__ float q[K_RANK_];
    __shared__ int   cidx[COARSE_K];
    __shared__ float sc[COARSE_K];
    __shared__ int   selg[FINE_K];
    __shared__ float selsc[FINE_K];

    if (tid < RANK) hrow[tid] = h[(size_t)tt * RANK + tid];
    if (tid < COARSE_K) {
        u64 k = R[(size_t)tt * COARSE_K + tid];
        cidx[tid] = (N_KNOW - 1) - (int)(u32)(k & 0xFFFFFFFFu);
    }
    __syncthreads();

    if (tid < K_RANK_) {
        float ss = 0.f;
        const float* wr = Wq + (size_t)tid * RANK;
#pragma unroll 8
        for (int r = 0; r < RANK; ++r) ss = fmaf(hrow[r], wr[r], ss);
        q[tid] = ss;
    }
    __syncthreads();

    {
        int c = tid >> 2, part = tid & 3;
        const float* kr = Kall + (size_t)cidx[c] * K_RANK_ + part * 32;
        const float* qp = q + part * 32;
        float ss = 0.f;
#pragma unroll 8
        for (int r = 0; r < 32; ++r) ss = fmaf(qp[r], kr[r], ss);
        ss += __shfl_xor(ss, 1, 4);
        ss += __shfl_xor(ss, 2, 4);
        if (part == 0) sc[c] = ss * 0.08838834764831845f;
    }
    __syncthreads();

    if (tid < COARSE_K) {
        float v = sc[tid];
        u64 k = ((u64)ordf(v) << 32) | (u32)(63 - tid);
        int r = 0;
        for (int j = 0; j < 64; ++j) {
            u64 kj = __shfl(k, j);
            r += (kj > k) ? 1 : 0;
        }
        if (r < FINE_K) { selg[r] = cidx[tid]; selsc[r] = v; }
    }
    __syncthreads();

    if (tid < FINE_K) {
        float e = expf(selsc[tid] - selsc[0]);
        float ssum = e;
        ssum += __shfl_xor(ssum, 1, 16);
        ssum += __shfl_xor(ssum, 2, 16);
        ssum += __shfl_xor(ssum, 4, 16);
        ssum += __shfl_xor(ssum, 8, 16);
        fidx[(size_t)tt * FINE_K + tid] = selg[tid];
        fw[(size_t)tt * FINE_K + tid] = e / ssum;
    }
}

// ---------------------------------------------------------------------------
__global__ __launch_bounds__(256)
void k3b(const int* __restrict__ fidx, const float* __restrict__ fw,
         const float* __restrict__ Vall, float* __restrict__ out)
{
    const int tt = blockIdx.x;
    const int tid = threadIdx.x;
    __shared__ int sidx[FINE_K];
    __shared__ float sw_[FINE_K];
    if (tid < FINE_K) {
        sidx[tid] = fidx[(size_t)tt * FINE_K + tid];
        sw_[tid] = fw[(size_t)tt * FINE_K + tid];
    }
    __syncthreads();

    float4 o = make_float4(0.f, 0.f, 0.f, 0.f);
#pragma unroll
    for (int f = 0; f < FINE_K; ++f) {
        float wf = sw_[f];
        const float4 vv = *(const float4*)(Vall + (size_t)sidx[f] * D_MODEL + tid * 4);
        o.x = fmaf(wf, vv.x, o.x);
        o.y = fmaf(wf, vv.y, o.y);
        o.z = fmaf(wf, vv.z, o.z);
        o.w = fmaf(wf, vv.w, o.w);
    }
    *(float4*)(out + (size_t)tt * D_MODEL + tid * 4) = o;
}

// ---------------------------------------------------------------------------
extern "C" void kernel_launch(void* const* d_in, const int* in_sizes, int n_in,
                              void* d_out, int out_size, void* d_ws, size_t ws_size,
                              hipStream_t stream)
{
    const float* x  = (const float*)d_in[0];
    const float* h  = (const float*)d_in[1];
    const float* Wr = (const float*)d_in[2];
    const float* Wq = (const float*)d_in[3];
    const float* Ka = (const float*)d_in[4];
    const float* Va = (const float*)d_in[5];
    float* out = (float*)d_out;

    char* p = (char*)d_ws;
    ushort* wt   = (ushort*)p;  p += (size_t)SC * D_MODEL * 2;         // 8 MB
    ushort* xh   = (ushort*)p;  p += (size_t)NTOK * D_MODEL * 2;       // 8 MB
    float*  L    = (float*)p;   p += (size_t)NTOK * SC * 4;            // 64 MB
    u64*    R96  = (u64*)p;     p += (size_t)NTOK * MSEL * 8;          // 3 MB
    u64*    nk   = (u64*)p;     p += (size_t)NTOK * MSEL * 8;          // 3 MB
    u64*    R64  = (u64*)p;     p += (size_t)NTOK * COARSE_K * 8;      // 2 MB
    int*    cnt  = (int*)p;     p += (size_t)NTOK * 4;
    u32*    jobs = (u32*)p;     p += (size_t)NTOK * MSEL * 4;          // 1.5 MB
    int*    jobCount = (int*)p; p += 64;
    u32*    band = (u32*)p;     p += (size_t)NTOK * 4;
    int*    fidx = (int*)p;     p += (size_t)NTOK * FINE_K * 4;
    float*  fw   = (float*)p;   p += (size_t)NTOK * FINE_K * 4;
    u64*    ovf  = (u64*)L;     // alias: L dead after stripe-0 k2_topk

    hipMemsetAsync(cnt, 0, (size_t)NTOK * 4, stream);
    hipMemsetAsync(jobCount, 0, 4, stream);

    kcvt_x<<<NTOK * D_MODEL / 4 / 256, 256, 0, stream>>>(x, xh);

    // stripe 0: dense logits + full top-96 scan
    kcvt_wt<<<dim3(SC / 32, D_MODEL / 32), 256, 0, stream>>>(Wr, wt, 0);
    k1f<0><<<dim3(SC / 128, NTOK / 128), 256, 0, stream>>>(
        xh, wt, L, nullptr, nullptr, nullptr, 0);
    k2_topk<MSEL, SC / 256><<<NTOK, 256, 0, stream>>>(L, R96, 0);

    // stripes 1..7: fused filter + merge
    for (int s = 1; s < N_KNOW / SC; ++s) {
        kcvt_wt<<<dim3(SC / 32, D_MODEL / 32), 256, 0, stream>>>(Wr, wt, s * SC);
        k1f<1><<<dim3(SC / 128, NTOK / 128), 256, 0, stream>>>(
            xh, wt, nullptr, ovf, cnt, R96, s * SC);
        k2m<<<NTOK, 256, 0, stream>>>(R96, ovf, cnt);
    }

    // repair pipeline (exact f32 within DELTA band)
    k2b_band<<<NTOK / 4, 256, 0, stream>>>(R96, jobs, jobCount, band);
    k2b_exec<<<8192, 256, 0, stream>>>(jobs, jobCount, R96, x, Wr, nk);
    k2b_final<<<NTOK, 128, 0, stream>>>(R96, nk, band, R64);

    k3a<<<NTOK, 256, 0, stream>>>(h, Wq, Ka, R64, fidx, fw);
    k3b<<<NTOK, 256, 0, stream>>>(fidx, fw, Va, out);
}

// Round 6
// 880.984 us; speedup vs baseline: 1.1339x; 1.1339x over previous
//
#include <hip/hip_runtime.h>
#include <cstdint>

#define D_MODEL 1024
#define RANK 128
#define K_RANK_ 128
#define N_KNOW 32768
#define COARSE_K 64
#define FINE_K 16
#define NTOK 4096
#define MSEL 96
#define DELTA 1.6e-3f
#define SC 4096

using u32 = unsigned int;
using u64 = unsigned long long;
typedef _Float16 half8 __attribute__((ext_vector_type(8)));
typedef __attribute__((ext_vector_type(4))) float f32x4;

__device__ __forceinline__ u32 ordf(float v) {
    u32 u = __float_as_uint(v);
    return (u & 0x80000000u) ? ~u : (u | 0x80000000u);
}
__device__ __forceinline__ float unordf(u32 o) {
    return (o & 0x80000000u) ? __uint_as_float(o ^ 0x80000000u)
                             : __uint_as_float(~o);
}
__device__ __forceinline__ ushort f2h(float f) {
    union { _Float16 h; ushort u; } cv; cv.h = (_Float16)f; return cv.u;
}
__device__ __forceinline__ void gload16(const void* g, void* l) {
    __builtin_amdgcn_global_load_lds(
        (const __attribute__((address_space(1))) char*)g,
        (__attribute__((address_space(3))) char*)l, 16, 0, 0);
}

// ---------------------------------------------------------------------------
__global__ __launch_bounds__(256)
void kcvt_x(const float* __restrict__ in, ushort* __restrict__ xh)
{
    int i = blockIdx.x * 256 + threadIdx.x;
    float4 v = ((const float4*)in)[i];
    ((ushort4*)xh)[i] = make_ushort4(f2h(v.x), f2h(v.y), f2h(v.z), f2h(v.w));
}

// ---------------------------------------------------------------------------
__global__ __launch_bounds__(256)
void kcvt_wt(const float* __restrict__ W, ushort* __restrict__ out, int col0)
{
    __shared__ float tile[32][33];
    const int nb = blockIdx.x * 32;
    const int kb = blockIdx.y * 32;
    const int tx = threadIdx.x & 31, ty = threadIdx.x >> 5;
#pragma unroll
    for (int q = 0; q < 4; ++q)
        tile[ty + q * 8][tx] = W[(size_t)(kb + ty + q * 8) * N_KNOW + col0 + nb + tx];
    __syncthreads();
#pragma unroll
    for (int q = 0; q < 4; ++q) {
        float v = tile[tx][ty + q * 8];
        out[(size_t)(nb + ty + q * 8) * D_MODEL + kb + tx] = f2h(v);
    }
}

// ---------------------------------------------------------------------------
// K1f8: fp16 MFMA GEMM, 256x256 tile, BK=64, 512 threads (8 waves 2Mx4N),
// double-buffered 128KB LDS, global_load_lds w16, counted vmcnt(8) pipeline
// (2 K-tiles in flight, never drain to 0 in the main loop), raw s_barrier,
// slot-XOR conflict-free LDS swizzle (inverse-swizzled global source),
// setprio around MFMA cluster, XCD-bijective block swizzle.
// Dense f32 logits out (stripe-local cols).
// ---------------------------------------------------------------------------
__global__ __launch_bounds__(512, 2)
void k1f8(const ushort* __restrict__ xh, const ushort* __restrict__ wt,
          float* __restrict__ L)
{
    __shared__ ushort lds[2][32768];   // [buf][A 256x64 | B 256x64] fp16

    const int tid = threadIdx.x;
    const int nwg = gridDim.x;                       // 256
    int wfl = blockIdx.x;
    wfl = (wfl & 7) * (nwg >> 3) + (wfl >> 3);       // XCD bijective swizzle
    const int bm = (wfl & 15) * 256;
    const int bn = (wfl >> 4) * 256;

    const int lane = tid & 63;
    const int wid = tid >> 6;
    const int wm = wid >> 2, wn = wid & 3;
    const int lr = lane & 15, g = lane >> 4;

    // staging sources, inverse-swizzled so linear LDS dest + swizzled read match
    const ushort* gA[4]; const ushort* gB[4];
#pragma unroll
    for (int i = 0; i < 4; ++i) {
        const int o = i * 512 + tid;                 // 0..2047
        const int row = o >> 3;                      // 0..255
        const int gslot = (o & 7) ^ (row & 7);       // involution
        gA[i] = xh + (size_t)(bm + row) * D_MODEL + gslot * 8;
        gB[i] = wt + (size_t)(bn + row) * D_MODEL + gslot * 8;
    }

    // swizzled ds_read byte offsets (A at 0, B at byte 32768)
    int aoff[2][8], boff[2][4];
#pragma unroll
    for (int ks = 0; ks < 2; ++ks) {
#pragma unroll
        for (int mf = 0; mf < 8; ++mf) {
            int row = wm * 128 + mf * 16 + lr;
            aoff[ks][mf] = row * 128 + (((ks * 4 + g) ^ (row & 7)) << 4);
        }
#pragma unroll
        for (int nf = 0; nf < 4; ++nf) {
            int row = wn * 64 + nf * 16 + lr;
            boff[ks][nf] = 32768 + row * 128 + (((ks * 4 + g) ^ (row & 7)) << 4);
        }
    }

    f32x4 acc[8][4];
#pragma unroll
    for (int mf = 0; mf < 8; ++mf)
#pragma unroll
        for (int nf = 0; nf < 4; ++nf) acc[mf][nf] = (f32x4)(0.f);

#define STAGE(buf, kt)                                                         \
    {                                                                          \
        const int kadd = (kt) * 64;                                            \
        _Pragma("unroll")                                                      \
        for (int i = 0; i < 4; ++i) {                                          \
            gload16(gA[i] + kadd, (char*)&lds[(buf)][0] + (i * 512 + tid) * 16);\
            gload16(gB[i] + kadd,                                              \
                    (char*)&lds[(buf)][0] + 32768 + (i * 512 + tid) * 16);     \
        }                                                                      \
    }

    STAGE(0, 0);
    STAGE(1, 1);

    const int NKT = D_MODEL / 64;    // 16
    for (int kt = 0; kt < NKT; ++kt) {
        if (kt < NKT - 1) asm volatile("s_waitcnt vmcnt(8)" ::: "memory");
        else              asm volatile("s_waitcnt vmcnt(0)" ::: "memory");
        __builtin_amdgcn_s_barrier();
        asm volatile("" ::: "memory");

        const char* lb = (const char*)&lds[kt & 1][0];
#pragma unroll
        for (int ks = 0; ks < 2; ++ks) {
            half8 a[8], b[4];
#pragma unroll
            for (int mf = 0; mf < 8; ++mf)
                a[mf] = *(const half8*)(lb + aoff[ks][mf]);
#pragma unroll
            for (int nf = 0; nf < 4; ++nf)
                b[nf] = *(const half8*)(lb + boff[ks][nf]);
            __builtin_amdgcn_s_setprio(1);
#pragma unroll
            for (int mf = 0; mf < 8; ++mf)
#pragma unroll
                for (int nf = 0; nf < 4; ++nf)
                    acc[mf][nf] = __builtin_amdgcn_mfma_f32_16x16x32_f16(
                        a[mf], b[nf], acc[mf][nf], 0, 0, 0);
            __builtin_amdgcn_s_setprio(0);
        }

        asm volatile("" ::: "memory");
        __builtin_amdgcn_s_barrier();
        asm volatile("" ::: "memory");
        if (kt + 2 < NKT) STAGE(kt & 1, kt + 2);
    }
#undef STAGE

    const int crow0 = bm + wm * 128 + g * 4;
    const int ccol  = bn + wn * 64 + lr;
#pragma unroll
    for (int mf = 0; mf < 8; ++mf)
#pragma unroll
        for (int nf = 0; nf < 4; ++nf)
#pragma unroll
            for (int r = 0; r < 4; ++r)
                L[(size_t)(crow0 + mf * 16 + r) * SC + ccol + nf * 16] = acc[mf][nf][r];
}

// ---------------------------------------------------------------------------
// K2: per-token running top-96 merge per stripe; float4-vectorized loads.
// ---------------------------------------------------------------------------
template <int M>
__global__ __launch_bounds__(256)
void k2_topk(const float* __restrict__ L, u64* __restrict__ R,
             int col0, int stripe)
{
    const int tt = blockIdx.x;
    const int tid = threadIdx.x;

    __shared__ u64 buf[4224];
    __shared__ int scnt;
    __shared__ int sred[4];

    u64 key[16];
    const float4* row4 = (const float4*)(L + (size_t)tt * SC);
#pragma unroll
    for (int q = 0; q < 4; ++q) {
        float4 v = row4[q * 256 + tid];
        int c = col0 + (q * 256 + tid) * 4;
        key[q * 4 + 0] = ((u64)ordf(v.x) << 32) | (u32)(N_KNOW - 1 - c);
        key[q * 4 + 1] = ((u64)ordf(v.y) << 32) | (u32)(N_KNOW - 2 - c);
        key[q * 4 + 2] = ((u64)ordf(v.z) << 32) | (u32)(N_KNOW - 3 - c);
        key[q * 4 + 3] = ((u64)ordf(v.w) << 32) | (u32)(N_KNOW - 4 - c);
    }

    u64 tkey;
    if (stripe == 0) {
        u32 lo = 0, hi = 0xFFFFFFFFu;
        for (int it = 0; it < 28; ++it) {
            if (hi - lo <= 1) break;
            u32 mid = lo + ((hi - lo) >> 1);
            int c = 0;
#pragma unroll
            for (int j = 0; j < 16; ++j) c += ((u32)(key[j] >> 32) > mid) ? 1 : 0;
#pragma unroll
            for (int o = 32; o; o >>= 1) c += __shfl_xor(c, o);
            if ((tid & 63) == 0) sred[tid >> 6] = c;
            __syncthreads();
            c = sred[0] + sred[1] + sred[2] + sred[3];
            __syncthreads();
            if (c >= M) { lo = mid; if (c <= 768) break; }
            else hi = mid;
        }
        tkey = ((u64)lo << 32) | 0xFFFFFFFFull;
        if (tid == 0) scnt = 0;
    } else {
        tkey = R[(size_t)tt * M + (M - 1)];
        if (tid < M) buf[tid] = R[(size_t)tt * M + tid];
        if (tid == 0) scnt = M;
    }
    __syncthreads();

#pragma unroll
    for (int j = 0; j < 16; ++j)
        if (key[j] > tkey) {
            int p = atomicAdd(&scnt, 1);
            if (p < 4224) buf[p] = key[j];
        }
    __syncthreads();

    const int n = min(scnt, 4224);
    for (int i = tid; i < n; i += 256) {
        u64 ki = buf[i];
        int r = 0;
        for (int j = 0; j < n; ++j) r += (buf[j] > ki) ? 1 : 0;
        if (r < M) R[(size_t)tt * M + r] = ki;
    }
}

// ---------------------------------------------------------------------------
// K2b pipeline: band -> exec (parallel exact f32 re-score) -> final
// ---------------------------------------------------------------------------
__global__ __launch_bounds__(256)
void k2b_band(const u64* __restrict__ R96, u32* __restrict__ jobs,
              int* __restrict__ jobCount, u32* __restrict__ band)
{
    __shared__ float sv[4][MSEL];
    const int tid = threadIdx.x;
    const int w = tid >> 6, lane = tid & 63;
    const int tt = blockIdx.x * 4 + w;

    sv[w][lane] = unordf((u32)(R96[(size_t)tt * MSEL + lane] >> 32));
    if (lane < MSEL - 64)
        sv[w][lane + 64] = unordf((u32)(R96[(size_t)tt * MSEL + lane + 64] >> 32));
    __syncthreads();

    const float t = sv[w][COARSE_K - 1];
    int cg = 0, cl = 0;
    for (int j = lane; j < MSEL; j += 64) {
        cg += (sv[w][j] > t + DELTA) ? 1 : 0;
        cl += (sv[w][j] < t - DELTA) ? 1 : 0;
    }
#pragma unroll
    for (int o = 32; o; o >>= 1) { cg += __shfl_xor(cg, o); cl += __shfl_xor(cl, o); }

    int lo = cg, hi = MSEL - 1 - cl;
    if (lo > COARSE_K - 1) lo = COARSE_K - 1;
    if (hi < COARSE_K - 1) hi = COARSE_K - 1;

    u32 b;
    if (lo == COARSE_K - 1 && hi == COARSE_K - 1) {
        b = 0x80000000u | 63u | (63u << 8);
    } else {
        int nj = hi - lo + 1;
        int base = 0;
        if (lane == 0) base = atomicAdd(jobCount, nj);
        base = __shfl(base, 0);
        for (int k = lane; k < nj; k += 64)
            jobs[base + k] = ((u32)tt << 8) | (u32)(lo + k);
        b = (u32)lo | ((u32)hi << 8);
    }
    if (lane == 0) band[tt] = b;
}

__global__ __launch_bounds__(256)
void k2b_exec(const u32* __restrict__ jobs, const int* __restrict__ jobCount,
              const u64* __restrict__ R96, const float* __restrict__ x,
              const float* __restrict__ W, u64* __restrict__ nk)
{
    __shared__ float red[4];
    const int tid = threadIdx.x;
    const int n = *jobCount;
    for (int j = blockIdx.x; j < n; j += gridDim.x) {
        u32 jd = jobs[j];
        int tt = jd >> 8, idx = jd & 255;
        u64 key = R96[(size_t)tt * MSEL + idx];
        int col = (N_KNOW - 1) - (int)(u32)(key & 0xFFFFFFFFu);
        float p = 0.f;
#pragma unroll
        for (int q = 0; q < 4; ++q) {
            int k = tid + q * 256;
            p = fmaf(x[(size_t)tt * D_MODEL + k], W[(size_t)k * N_KNOW + col], p);
        }
#pragma unroll
        for (int o = 32; o; o >>= 1) p += __shfl_xor(p, o);
        if ((tid & 63) == 0) red[tid >> 6] = p;
        __syncthreads();
        if (tid == 0) {
            float e = red[0] + red[1] + red[2] + red[3];
            nk[(size_t)tt * MSEL + idx] = ((u64)ordf(e) << 32) | (key & 0xFFFFFFFFu);
        }
        __syncthreads();
    }
}

__global__ __launch_bounds__(128)
void k2b_final(const u64* __restrict__ R96, const u64* __restrict__ nk,
               const u32* __restrict__ band, u64* __restrict__ R64)
{
    const int tt = blockIdx.x;
    const int tid = threadIdx.x;
    __shared__ u64 keys[MSEL];
    __shared__ u64 nkk[MSEL];

    const u32 b = band[tt];
    if (tid < MSEL) keys[tid] = R96[(size_t)tt * MSEL + tid];
    const int lo = b & 0xFF, hi = (b >> 8) & 0xFF;
    const bool trivial = (b & 0x80000000u) != 0;
    if (!trivial && tid >= lo && tid <= hi && tid < MSEL)
        nkk[tid] = nk[(size_t)tt * MSEL + tid];
    __syncthreads();

    if (trivial) {
        if (tid < COARSE_K) R64[(size_t)tt * COARSE_K + tid] = keys[tid];
        return;
    }
    if (tid < lo) R64[(size_t)tt * COARSE_K + tid] = keys[tid];
    const int mwin = COARSE_K - lo;
    if (tid >= lo && tid <= hi) {
        u64 me = nkk[tid];
        int r = 0;
        for (int j = lo; j <= hi; ++j) r += (nkk[j] > me) ? 1 : 0;
        if (r < mwin) R64[(size_t)tt * COARSE_K + lo + r] = keys[tid];
    }
}

// ---------------------------------------------------------------------------
// K3a: fine scores + top-16 + softmax weights
// ---------------------------------------------------------------------------
__global__ __launch_bounds__(256)
void k3a(const float* __restrict__ h, const float* __restrict__ Wq,
         const float* __restrict__ Kall, const u64* __restrict__ R,
         int* __restrict__ fidx, float* __restrict__ fw)
{
    const int tt = blockIdx.x;
    const int tid = threadIdx.x;

    __shared__ float hrow[RANK];
    __shared__ float q[K_RANK_];
    __shared__ int   cidx[COARSE_K];
    __shared__ float sc[COARSE_K];
    __shared__ int   selg[FINE_K];
    __shared__ float selsc[FINE_K];

    if (tid < RANK) hrow[tid] = h[(size_t)tt * RANK + tid];
    if (tid < COARSE_K) {
        u64 k = R[(size_t)tt * COARSE_K + tid];
        cidx[tid] = (N_KNOW - 1) - (int)(u32)(k & 0xFFFFFFFFu);
    }
    __syncthreads();

    if (tid < K_RANK_) {
        float ss = 0.f;
        const float* wr = Wq + (size_t)tid * RANK;
#pragma unroll 8
        for (int r = 0; r < RANK; ++r) ss = fmaf(hrow[r], wr[r], ss);
        q[tid] = ss;
    }
    __syncthreads();

    {
        int c = tid >> 2, part = tid & 3;
        const float* kr = Kall + (size_t)cidx[c] * K_RANK_ + part * 32;
        const float* qp = q + part * 32;
        float ss = 0.f;
#pragma unroll 8
        for (int r = 0; r < 32; ++r) ss = fmaf(qp[r], kr[r], ss);
        ss += __shfl_xor(ss, 1, 4);
        ss += __shfl_xor(ss, 2, 4);
        if (part == 0) sc[c] = ss * 0.08838834764831845f;
    }
    __syncthreads();

    if (tid < COARSE_K) {
        float v = sc[tid];
        u64 k = ((u64)ordf(v) << 32) | (u32)(63 - tid);
        int r = 0;
        for (int j = 0; j < 64; ++j) {
            u64 kj = __shfl(k, j);
            r += (kj > k) ? 1 : 0;
        }
        if (r < FINE_K) { selg[r] = cidx[tid]; selsc[r] = v; }
    }
    __syncthreads();

    if (tid < FINE_K) {
        float e = expf(selsc[tid] - selsc[0]);
        float ssum = e;
        ssum += __shfl_xor(ssum, 1, 16);
        ssum += __shfl_xor(ssum, 2, 16);
        ssum += __shfl_xor(ssum, 4, 16);
        ssum += __shfl_xor(ssum, 8, 16);
        fidx[(size_t)tt * FINE_K + tid] = selg[tid];
        fw[(size_t)tt * FINE_K + tid] = e / ssum;
    }
}

// ---------------------------------------------------------------------------
__global__ __launch_bounds__(256)
void k3b(const int* __restrict__ fidx, const float* __restrict__ fw,
         const float* __restrict__ Vall, float* __restrict__ out)
{
    const int tt = blockIdx.x;
    const int tid = threadIdx.x;
    __shared__ int sidx[FINE_K];
    __shared__ float sw_[FINE_K];
    if (tid < FINE_K) {
        sidx[tid] = fidx[(size_t)tt * FINE_K + tid];
        sw_[tid] = fw[(size_t)tt * FINE_K + tid];
    }
    __syncthreads();

    float4 o = make_float4(0.f, 0.f, 0.f, 0.f);
#pragma unroll
    for (int f = 0; f < FINE_K; ++f) {
        float wf = sw_[f];
        const float4 vv = *(const float4*)(Vall + (size_t)sidx[f] * D_MODEL + tid * 4);
        o.x = fmaf(wf, vv.x, o.x);
        o.y = fmaf(wf, vv.y, o.y);
        o.z = fmaf(wf, vv.z, o.z);
        o.w = fmaf(wf, vv.w, o.w);
    }
    *(float4*)(out + (size_t)tt * D_MODEL + tid * 4) = o;
}

// ---------------------------------------------------------------------------
extern "C" void kernel_launch(void* const* d_in, const int* in_sizes, int n_in,
                              void* d_out, int out_size, void* d_ws, size_t ws_size,
                              hipStream_t stream)
{
    const float* x  = (const float*)d_in[0];
    const float* h  = (const float*)d_in[1];
    const float* Wr = (const float*)d_in[2];
    const float* Wq = (const float*)d_in[3];
    const float* Ka = (const float*)d_in[4];
    const float* Va = (const float*)d_in[5];
    float* out = (float*)d_out;

    char* p = (char*)d_ws;
    ushort* wt   = (ushort*)p;  p += (size_t)SC * D_MODEL * 2;         // 8 MB
    ushort* xh   = (ushort*)p;  p += (size_t)NTOK * D_MODEL * 2;       // 8 MB
    float*  L    = (float*)p;   p += (size_t)NTOK * SC * 4;            // 64 MB
    u64*    R96  = (u64*)p;     p += (size_t)NTOK * MSEL * 8;          // 3 MB
    u64*    nk   = (u64*)p;     p += (size_t)NTOK * MSEL * 8;          // 3 MB
    u64*    R64  = (u64*)p;     p += (size_t)NTOK * COARSE_K * 8;      // 2 MB
    u32*    jobs = (u32*)p;     p += (size_t)NTOK * MSEL * 4;          // 1.5 MB
    int*    jobCount = (int*)p; p += 64;
    u32*    band = (u32*)p;     p += (size_t)NTOK * 4;
    int*    fidx = (int*)p;     p += (size_t)NTOK * FINE_K * 4;
    float*  fw   = (float*)p;   p += (size_t)NTOK * FINE_K * 4;

    hipMemsetAsync(jobCount, 0, 4, stream);

    kcvt_x<<<NTOK * D_MODEL / 4 / 256, 256, 0, stream>>>(x, xh);

    const int nstripe = N_KNOW / SC;
    for (int s = 0; s < nstripe; ++s) {
        kcvt_wt<<<dim3(SC / 32, D_MODEL / 32), 256, 0, stream>>>(Wr, wt, s * SC);
        k1f8<<<(SC / 256) * (NTOK / 256), 512, 0, stream>>>(xh, wt, L);
        k2_topk<MSEL><<<NTOK, 256, 0, stream>>>(L, R96, s * SC, s);
    }

    k2b_band<<<NTOK / 4, 256, 0, stream>>>(R96, jobs, jobCount, band);
    k2b_exec<<<8192, 256, 0, stream>>>(jobs, jobCount, R96, x, Wr, nk);
    k2b_final<<<NTOK, 128, 0, stream>>>(R96, nk, band, R64);

    k3a<<<NTOK, 256, 0, stream>>>(h, Wq, Ka, R64, fidx, fw);
    k3b<<<NTOK, 256, 0, stream>>>(fidx, fw, Va, out);
}

// Round 7
// 821.923 us; speedup vs baseline: 1.2154x; 1.0719x over previous
//
#include <hip/hip_runtime.h>
#include <cstdint>

#define D_MODEL 1024
#define RANK 128
#define K_RANK_ 128
#define N_KNOW 32768
#define COARSE_K 64
#define FINE_K 16
#define NTOK 4096
#define MSEL 96
#define DELTA 1.0e-3f
#define SC 4096

using u32 = unsigned int;
using u64 = unsigned long long;
typedef _Float16 half8 __attribute__((ext_vector_type(8)));
typedef __attribute__((ext_vector_type(4))) float f32x4;

__device__ __forceinline__ u32 ordf(float v) {
    u32 u = __float_as_uint(v);
    return (u & 0x80000000u) ? ~u : (u | 0x80000000u);
}
__device__ __forceinline__ float unordf(u32 o) {
    return (o & 0x80000000u) ? __uint_as_float(o ^ 0x80000000u)
                             : __uint_as_float(~o);
}
__device__ __forceinline__ ushort f2h(float f) {
    union { _Float16 h; ushort u; } cv; cv.h = (_Float16)f; return cv.u;
}
__device__ __forceinline__ void gload16(const void* g, void* l) {
    __builtin_amdgcn_global_load_lds(
        (const __attribute__((address_space(1))) char*)g,
        (__attribute__((address_space(3))) char*)l, 16, 0, 0);
}

// ---------------------------------------------------------------------------
__global__ __launch_bounds__(256)
void kcvt_x(const float* __restrict__ in, ushort* __restrict__ xh)
{
    int i = blockIdx.x * 256 + threadIdx.x;
    float4 v = ((const float4*)in)[i];
    ((ushort4*)xh)[i] = make_ushort4(f2h(v.x), f2h(v.y), f2h(v.z), f2h(v.w));
}

// ---------------------------------------------------------------------------
__global__ __launch_bounds__(256)
void kcvt_wt(const float* __restrict__ W, ushort* __restrict__ out, int col0)
{
    __shared__ float tile[32][33];
    const int nb = blockIdx.x * 32;
    const int kb = blockIdx.y * 32;
    const int tx = threadIdx.x & 31, ty = threadIdx.x >> 5;
#pragma unroll
    for (int q = 0; q < 4; ++q)
        tile[ty + q * 8][tx] = W[(size_t)(kb + ty + q * 8) * N_KNOW + col0 + nb + tx];
    __syncthreads();
#pragma unroll
    for (int q = 0; q < 4; ++q) {
        float v = tile[tx][ty + q * 8];
        out[(size_t)(nb + ty + q * 8) * D_MODEL + kb + tx] = f2h(v);
    }
}

// ---------------------------------------------------------------------------
// K1f8: fp16 MFMA GEMM, 256x256 tile, BK=64, 512 threads (8 waves 2Mx4N),
// double-buffered 128KB LDS, global_load_lds w16, counted vmcnt(8) pipeline,
// raw s_barrier, slot-XOR conflict-free LDS swizzle, setprio, XCD swizzle.
// ---------------------------------------------------------------------------
__global__ __launch_bounds__(512, 2)
void k1f8(const ushort* __restrict__ xh, const ushort* __restrict__ wt,
          float* __restrict__ L)
{
    __shared__ ushort lds[2][32768];   // [buf][A 256x64 | B 256x64] fp16

    const int tid = threadIdx.x;
    const int nwg = gridDim.x;                       // 256
    int wfl = blockIdx.x;
    wfl = (wfl & 7) * (nwg >> 3) + (wfl >> 3);       // XCD bijective swizzle
    const int bm = (wfl & 15) * 256;
    const int bn = (wfl >> 4) * 256;

    const int lane = tid & 63;
    const int wid = tid >> 6;
    const int wm = wid >> 2, wn = wid & 3;
    const int lr = lane & 15, g = lane >> 4;

    const ushort* gA[4]; const ushort* gB[4];
#pragma unroll
    for (int i = 0; i < 4; ++i) {
        const int o = i * 512 + tid;                 // 0..2047
        const int row = o >> 3;                      // 0..255
        const int gslot = (o & 7) ^ (row & 7);       // involution
        gA[i] = xh + (size_t)(bm + row) * D_MODEL + gslot * 8;
        gB[i] = wt + (size_t)(bn + row) * D_MODEL + gslot * 8;
    }

    int aoff[2][8], boff[2][4];
#pragma unroll
    for (int ks = 0; ks < 2; ++ks) {
#pragma unroll
        for (int mf = 0; mf < 8; ++mf) {
            int row = wm * 128 + mf * 16 + lr;
            aoff[ks][mf] = row * 128 + (((ks * 4 + g) ^ (row & 7)) << 4);
        }
#pragma unroll
        for (int nf = 0; nf < 4; ++nf) {
            int row = wn * 64 + nf * 16 + lr;
            boff[ks][nf] = 32768 + row * 128 + (((ks * 4 + g) ^ (row & 7)) << 4);
        }
    }

    f32x4 acc[8][4];
#pragma unroll
    for (int mf = 0; mf < 8; ++mf)
#pragma unroll
        for (int nf = 0; nf < 4; ++nf) acc[mf][nf] = (f32x4)(0.f);

#define STAGE(buf, kt)                                                         \
    {                                                                          \
        const int kadd = (kt) * 64;                                            \
        _Pragma("unroll")                                                      \
        for (int i = 0; i < 4; ++i) {                                          \
            gload16(gA[i] + kadd, (char*)&lds[(buf)][0] + (i * 512 + tid) * 16);\
            gload16(gB[i] + kadd,                                              \
                    (char*)&lds[(buf)][0] + 32768 + (i * 512 + tid) * 16);     \
        }                                                                      \
    }

    STAGE(0, 0);
    STAGE(1, 1);

    const int NKT = D_MODEL / 64;    // 16
    for (int kt = 0; kt < NKT; ++kt) {
        if (kt < NKT - 1) asm volatile("s_waitcnt vmcnt(8)" ::: "memory");
        else              asm volatile("s_waitcnt vmcnt(0)" ::: "memory");
        __builtin_amdgcn_s_barrier();
        asm volatile("" ::: "memory");

        const char* lb = (const char*)&lds[kt & 1][0];
#pragma unroll
        for (int ks = 0; ks < 2; ++ks) {
            half8 a[8], b[4];
#pragma unroll
            for (int mf = 0; mf < 8; ++mf)
                a[mf] = *(const half8*)(lb + aoff[ks][mf]);
#pragma unroll
            for (int nf = 0; nf < 4; ++nf)
                b[nf] = *(const half8*)(lb + boff[ks][nf]);
            __builtin_amdgcn_s_setprio(1);
#pragma unroll
            for (int mf = 0; mf < 8; ++mf)
#pragma unroll
                for (int nf = 0; nf < 4; ++nf)
                    acc[mf][nf] = __builtin_amdgcn_mfma_f32_16x16x32_f16(
                        a[mf], b[nf], acc[mf][nf], 0, 0, 0);
            __builtin_amdgcn_s_setprio(0);
        }

        asm volatile("" ::: "memory");
        __builtin_amdgcn_s_barrier();
        asm volatile("" ::: "memory");
        if (kt + 2 < NKT) STAGE(kt & 1, kt + 2);
    }
#undef STAGE

    const int crow0 = bm + wm * 128 + g * 4;
    const int ccol  = bn + wn * 64 + lr;
#pragma unroll
    for (int mf = 0; mf < 8; ++mf)
#pragma unroll
        for (int nf = 0; nf < 4; ++nf)
#pragma unroll
            for (int r = 0; r < 4; ++r)
                L[(size_t)(crow0 + mf * 16 + r) * SC + ccol + nf * 16] = acc[mf][nf][r];
}

// ---------------------------------------------------------------------------
// K2: per-token running top-96 merge per stripe; float4-vectorized loads.
// ---------------------------------------------------------------------------
template <int M>
__global__ __launch_bounds__(256)
void k2_topk(const float* __restrict__ L, u64* __restrict__ R,
             int col0, int stripe)
{
    const int tt = blockIdx.x;
    const int tid = threadIdx.x;

    __shared__ u64 buf[4224];
    __shared__ int scnt;
    __shared__ int sred[4];

    u64 key[16];
    const float4* row4 = (const float4*)(L + (size_t)tt * SC);
#pragma unroll
    for (int q = 0; q < 4; ++q) {
        float4 v = row4[q * 256 + tid];
        int c = col0 + (q * 256 + tid) * 4;
        key[q * 4 + 0] = ((u64)ordf(v.x) << 32) | (u32)(N_KNOW - 1 - c);
        key[q * 4 + 1] = ((u64)ordf(v.y) << 32) | (u32)(N_KNOW - 2 - c);
        key[q * 4 + 2] = ((u64)ordf(v.z) << 32) | (u32)(N_KNOW - 3 - c);
        key[q * 4 + 3] = ((u64)ordf(v.w) << 32) | (u32)(N_KNOW - 4 - c);
    }

    u64 tkey;
    if (stripe == 0) {
        u32 lo = 0, hi = 0xFFFFFFFFu;
        for (int it = 0; it < 28; ++it) {
            if (hi - lo <= 1) break;
            u32 mid = lo + ((hi - lo) >> 1);
            int c = 0;
#pragma unroll
            for (int j = 0; j < 16; ++j) c += ((u32)(key[j] >> 32) > mid) ? 1 : 0;
#pragma unroll
            for (int o = 32; o; o >>= 1) c += __shfl_xor(c, o);
            if ((tid & 63) == 0) sred[tid >> 6] = c;
            __syncthreads();
            c = sred[0] + sred[1] + sred[2] + sred[3];
            __syncthreads();
            if (c >= M) { lo = mid; if (c <= 768) break; }
            else hi = mid;
        }
        tkey = ((u64)lo << 32) | 0xFFFFFFFFull;
        if (tid == 0) scnt = 0;
    } else {
        tkey = R[(size_t)tt * M + (M - 1)];
        if (tid < M) buf[tid] = R[(size_t)tt * M + tid];
        if (tid == 0) scnt = M;
    }
    __syncthreads();

#pragma unroll
    for (int j = 0; j < 16; ++j)
        if (key[j] > tkey) {
            int p = atomicAdd(&scnt, 1);
            if (p < 4224) buf[p] = key[j];
        }
    __syncthreads();

    const int n = min(scnt, 4224);
    for (int i = tid; i < n; i += 256) {
        u64 ki = buf[i];
        int r = 0;
        for (int j = 0; j < n; ++j) r += (buf[j] > ki) ? 1 : 0;
        if (r < M) R[(size_t)tt * M + r] = ki;
    }
}

// ---------------------------------------------------------------------------
// K2b pipeline: band -> exec (parallel exact f32 re-score) -> final
// ---------------------------------------------------------------------------
__global__ __launch_bounds__(256)
void k2b_band(const u64* __restrict__ R96, u32* __restrict__ jobs,
              int* __restrict__ jobCount, u32* __restrict__ band)
{
    __shared__ float sv[4][MSEL];
    const int tid = threadIdx.x;
    const int w = tid >> 6, lane = tid & 63;
    const int tt = blockIdx.x * 4 + w;

    sv[w][lane] = unordf((u32)(R96[(size_t)tt * MSEL + lane] >> 32));
    if (lane < MSEL - 64)
        sv[w][lane + 64] = unordf((u32)(R96[(size_t)tt * MSEL + lane + 64] >> 32));
    __syncthreads();

    const float t = sv[w][COARSE_K - 1];
    int cg = 0, cl = 0;
    for (int j = lane; j < MSEL; j += 64) {
        cg += (sv[w][j] > t + DELTA) ? 1 : 0;
        cl += (sv[w][j] < t - DELTA) ? 1 : 0;
    }
#pragma unroll
    for (int o = 32; o; o >>= 1) { cg += __shfl_xor(cg, o); cl += __shfl_xor(cl, o); }

    int lo = cg, hi = MSEL - 1 - cl;
    if (lo > COARSE_K - 1) lo = COARSE_K - 1;
    if (hi < COARSE_K - 1) hi = COARSE_K - 1;

    u32 b;
    if (lo == COARSE_K - 1 && hi == COARSE_K - 1) {
        b = 0x80000000u | 63u | (63u << 8);
    } else {
        int nj = hi - lo + 1;
        int base = 0;
        if (lane == 0) base = atomicAdd(jobCount, nj);
        base = __shfl(base, 0);
        for (int k = lane; k < nj; k += 64)
            jobs[base + k] = ((u32)tt << 8) | (u32)(lo + k);
        b = (u32)lo | ((u32)hi << 8);
    }
    if (lane == 0) band[tt] = b;
}

__global__ __launch_bounds__(256)
void k2b_exec(const u32* __restrict__ jobs, const int* __restrict__ jobCount,
              const u64* __restrict__ R96, const float* __restrict__ x,
              const float* __restrict__ W, u64* __restrict__ nk)
{
    __shared__ float red[4];
    const int tid = threadIdx.x;
    const int n = *jobCount;
    for (int j = blockIdx.x; j < n; j += gridDim.x) {
        u32 jd = jobs[j];
        int tt = jd >> 8, idx = jd & 255;
        u64 key = R96[(size_t)tt * MSEL + idx];
        int col = (N_KNOW - 1) - (int)(u32)(key & 0xFFFFFFFFu);
        float p = 0.f;
#pragma unroll
        for (int q = 0; q < 4; ++q) {
            int k = tid + q * 256;
            p = fmaf(x[(size_t)tt * D_MODEL + k], W[(size_t)k * N_KNOW + col], p);
        }
#pragma unroll
        for (int o = 32; o; o >>= 1) p += __shfl_xor(p, o);
        if ((tid & 63) == 0) red[tid >> 6] = p;
        __syncthreads();
        if (tid == 0) {
            float e = red[0] + red[1] + red[2] + red[3];
            nk[(size_t)tt * MSEL + idx] = ((u64)ordf(e) << 32) | (key & 0xFFFFFFFFu);
        }
        __syncthreads();
    }
}

__global__ __launch_bounds__(128)
void k2b_final(const u64* __restrict__ R96, const u64* __restrict__ nk,
               const u32* __restrict__ band, u64* __restrict__ R64)
{
    const int tt = blockIdx.x;
    const int tid = threadIdx.x;
    __shared__ u64 keys[MSEL];
    __shared__ u64 nkk[MSEL];

    const u32 b = band[tt];
    if (tid < MSEL) keys[tid] = R96[(size_t)tt * MSEL + tid];
    const int lo = b & 0xFF, hi = (b >> 8) & 0xFF;
    const bool trivial = (b & 0x80000000u) != 0;
    if (!trivial && tid >= lo && tid <= hi && tid < MSEL)
        nkk[tid] = nk[(size_t)tt * MSEL + tid];
    __syncthreads();

    if (trivial) {
        if (tid < COARSE_K) R64[(size_t)tt * COARSE_K + tid] = keys[tid];
        return;
    }
    if (tid < lo) R64[(size_t)tt * COARSE_K + tid] = keys[tid];
    const int mwin = COARSE_K - lo;
    if (tid >= lo && tid <= hi) {
        u64 me = nkk[tid];
        int r = 0;
        for (int j = lo; j <= hi; ++j) r += (nkk[j] > me) ? 1 : 0;
        if (r < mwin) R64[(size_t)tt * COARSE_K + lo + r] = keys[tid];
    }
}

// ---------------------------------------------------------------------------
// K3 fused: one wave per token (4 tokens/block). q via 2 elems/lane,
// fine score 1 cand/lane, wave-shuffle rank + softmax, coalesced V combine.
// ---------------------------------------------------------------------------
__device__ __forceinline__ void fma4(float4& a, float w, const float4& v) {
    a.x = fmaf(w, v.x, a.x); a.y = fmaf(w, v.y, a.y);
    a.z = fmaf(w, v.z, a.z); a.w = fmaf(w, v.w, a.w);
}

__global__ __launch_bounds__(256)
void k3(const float* __restrict__ h, const float* __restrict__ Wq,
        const float* __restrict__ Kall, const float* __restrict__ Vall,
        const u64* __restrict__ R, float* __restrict__ out)
{
    __shared__ float hq[4][RANK];
    __shared__ float qv[4][K_RANK_];
    __shared__ float selw[4][FINE_K];
    __shared__ int   seli[4][FINE_K];

    const int tid = threadIdx.x;
    const int w = tid >> 6, lane = tid & 63;
    const int tt = blockIdx.x * 4 + w;

    {   // h row + own candidate
        float2 hv = *(const float2*)(h + (size_t)tt * RANK + lane * 2);
        hq[w][lane * 2] = hv.x;
        hq[w][lane * 2 + 1] = hv.y;
    }
    const u64 key = R[(size_t)tt * COARSE_K + lane];
    const int ci = (N_KNOW - 1) - (int)(u32)(key & 0xFFFFFFFFu);
    __syncthreads();

    {   // q[2*lane], q[2*lane+1] = Wq rows . h
        float s0 = 0.f, s1 = 0.f;
        const float4* w0 = (const float4*)(Wq + (size_t)(lane * 2) * RANK);
        const float4* w1 = (const float4*)(Wq + (size_t)(lane * 2 + 1) * RANK);
#pragma unroll
        for (int r4 = 0; r4 < RANK / 4; ++r4) {
            float4 a = w0[r4], b = w1[r4];
            const float* hh = &hq[w][r4 * 4];
            s0 = fmaf(a.x, hh[0], s0); s0 = fmaf(a.y, hh[1], s0);
            s0 = fmaf(a.z, hh[2], s0); s0 = fmaf(a.w, hh[3], s0);
            s1 = fmaf(b.x, hh[0], s1); s1 = fmaf(b.y, hh[1], s1);
            s1 = fmaf(b.z, hh[2], s1); s1 = fmaf(b.w, hh[3], s1);
        }
        qv[w][lane * 2] = s0;
        qv[w][lane * 2 + 1] = s1;
    }
    __syncthreads();

    float sc;
    {   // fine score for own candidate
        float s = 0.f;
        const float4* kr = (const float4*)(Kall + (size_t)ci * K_RANK_);
#pragma unroll
        for (int r4 = 0; r4 < K_RANK_ / 4; ++r4) {
            float4 a = kr[r4];
            const float* qq = &qv[w][r4 * 4];
            s = fmaf(a.x, qq[0], s); s = fmaf(a.y, qq[1], s);
            s = fmaf(a.z, qq[2], s); s = fmaf(a.w, qq[3], s);
        }
        sc = s * 0.08838834764831845f;   // 1/sqrt(128)
    }

    // wave rank (key: score desc, lower local idx wins ties)
    const u64 myk = ((u64)ordf(sc) << 32) | (u32)(63 - lane);
    int rnk = 0;
#pragma unroll
    for (int j = 0; j < 64; ++j) {
        u64 kj = __shfl(myk, j);
        rnk += (kj > myk) ? 1 : 0;
    }

    // softmax over top-16 winners (max = wave max = rank0 score)
    float smax = sc;
#pragma unroll
    for (int o = 32; o; o >>= 1) smax = fmaxf(smax, __shfl_xor(smax, o));
    float e = (rnk < FINE_K) ? expf(sc - smax) : 0.f;
    float esum = e;
#pragma unroll
    for (int o = 32; o; o >>= 1) esum += __shfl_xor(esum, o);
    if (rnk < FINE_K) {
        seli[w][rnk] = ci;
        selw[w][rnk] = e / esum;
    }
    __syncthreads();

    // weighted V combine: lane owns cols {4l, 4l+256, 4l+512, 4l+768}
    float4 a0 = make_float4(0.f, 0.f, 0.f, 0.f), a1 = a0, a2 = a0, a3 = a0;
#pragma unroll
    for (int f = 0; f < FINE_K; ++f) {
        const float wf = selw[w][f];
        const float4* vr = (const float4*)(Vall + (size_t)seli[w][f] * D_MODEL);
        fma4(a0, wf, vr[lane]);
        fma4(a1, wf, vr[lane + 64]);
        fma4(a2, wf, vr[lane + 128]);
        fma4(a3, wf, vr[lane + 192]);
    }
    float4* op = (float4*)(out + (size_t)tt * D_MODEL);
    op[lane]       = a0;
    op[lane + 64]  = a1;
    op[lane + 128] = a2;
    op[lane + 192] = a3;
}

// ---------------------------------------------------------------------------
extern "C" void kernel_launch(void* const* d_in, const int* in_sizes, int n_in,
                              void* d_out, int out_size, void* d_ws, size_t ws_size,
                              hipStream_t stream)
{
    const float* x  = (const float*)d_in[0];
    const float* h  = (const float*)d_in[1];
    const float* Wr = (const float*)d_in[2];
    const float* Wq = (const float*)d_in[3];
    const float* Ka = (const float*)d_in[4];
    const float* Va = (const float*)d_in[5];
    float* out = (float*)d_out;

    char* p = (char*)d_ws;
    ushort* wt   = (ushort*)p;  p += (size_t)SC * D_MODEL * 2;         // 8 MB
    ushort* xh   = (ushort*)p;  p += (size_t)NTOK * D_MODEL * 2;       // 8 MB
    float*  L    = (float*)p;   p += (size_t)NTOK * SC * 4;            // 64 MB
    u64*    R96  = (u64*)p;     p += (size_t)NTOK * MSEL * 8;          // 3 MB
    u64*    nk   = (u64*)p;     p += (size_t)NTOK * MSEL * 8;          // 3 MB
    u64*    R64  = (u64*)p;     p += (size_t)NTOK * COARSE_K * 8;      // 2 MB
    u32*    jobs = (u32*)p;     p += (size_t)NTOK * MSEL * 4;          // 1.5 MB
    int*    jobCount = (int*)p; p += 64;
    u32*    band = (u32*)p;     p += (size_t)NTOK * 4;

    hipMemsetAsync(jobCount, 0, 4, stream);

    kcvt_x<<<NTOK * D_MODEL / 4 / 256, 256, 0, stream>>>(x, xh);

    const int nstripe = N_KNOW / SC;
    for (int s = 0; s < nstripe; ++s) {
        kcvt_wt<<<dim3(SC / 32, D_MODEL / 32), 256, 0, stream>>>(Wr, wt, s * SC);
        k1f8<<<(SC / 256) * (NTOK / 256), 512, 0, stream>>>(xh, wt, L);
        k2_topk<MSEL><<<NTOK, 256, 0, stream>>>(L, R96, s * SC, s);
    }

    k2b_band<<<NTOK / 4, 256, 0, stream>>>(R96, jobs, jobCount, band);
    k2b_exec<<<8192, 256, 0, stream>>>(jobs, jobCount, R96, x, Wr, nk);
    k2b_final<<<NTOK, 128, 0, stream>>>(R96, nk, band, R64);

    k3<<<NTOK / 4, 256, 0, stream>>>(h, Wq, Ka, Va, R64, out);
}